// Round 1
// baseline (2006.583 us; speedup 1.0000x reference)
//
#include <hip/hip_runtime.h>

// ---------------- workspace layout (floats) ----------------
#define WS_Q    0        // Q[18][27] = P @ ra_w
#define WS_BZ1  486      // bias_z1[5][18]
#define WS_BX1  576      // biasX1[25][18]
#define WS_SP   1026     // S_P[18]
#define WS_SB   1044     // Sb[125] = row sums of convb_w
#define WS_W3T  1172     // w3t[50][80]   (k=cin*2+dh, padded to 80)
#define WS_W4T  5172     // w4t[150][128] (k=cin*2+dh, padded to 128)
#define WS_WBT  24372    // wbt[75][128]  (k=cin*3+dh, padded to 128)
#define WS_TOTAL 33972

// ---------------- precompute kernel ----------------
__global__ void precompute_kernel(
    const float* __restrict__ conv1_b, const float* __restrict__ l1_w, const float* __restrict__ l1_b,
    const float* __restrict__ conv2_b, const float* __restrict__ ra_w, const float* __restrict__ ra_b,
    const float* __restrict__ conva_w, const float* __restrict__ conva_b,
    const float* __restrict__ conv3_w, const float* __restrict__ l2_w,
    const float* __restrict__ conv4_w, const float* __restrict__ rb_w,
    const float* __restrict__ convb_w, float* __restrict__ ws)
{
    int t = blockIdx.x * blockDim.x + threadIdx.x;
    int stride = gridDim.x * blockDim.x;
    // P[j][o], j<18, o<18: rows = concat(l2_w, rb_w)
    auto P = [&](int j, int o) -> float {
        return (j < 9) ? l2_w[j * 18 + o] : rb_w[(j - 9) * 18 + o];
    };
    for (int idx = t; idx < 486; idx += stride) {           // Q = P @ ra_w  [18][27]
        int j = idx / 27, w = idx % 27;
        float s = 0.f;
        for (int o = 0; o < 18; o++) s += P(j, o) * ra_w[o * 27 + w];
        ws[WS_Q + idx] = s;
    }
    for (int idx = t; idx < 90; idx += stride) {            // bias_z1[c][o]
        int c = idx / 18, o = idx % 18;
        float sl = 0.f;
        for (int w = 0; w < 27; w++) sl += l1_w[o * 27 + w];
        ws[WS_BZ1 + idx] = conv1_b[c] * sl + l1_b[o];
    }
    for (int idx = t; idx < 450; idx += stride) {           // biasX1[o][j]
        int o = idx / 18, j = idx % 18;
        float sp = 0.f, rab = 0.f;
        for (int w = 0; w < 18; w++) { float p = P(j, w); sp += p; rab += ra_b[w] * p; }
        ws[WS_BX1 + idx] = conv2_b[o] * sp + conva_w[o] * rab + conva_b[o] * sp;
    }
    for (int idx = t; idx < 18; idx += stride) {            // S_P[j]
        float sp = 0.f;
        for (int w = 0; w < 18; w++) sp += P(idx, w);
        ws[WS_SP + idx] = sp;
    }
    for (int idx = t; idx < 125; idx += stride) {           // Sb[o]
        float s = 0.f;
        for (int k = 0; k < 75; k++) s += convb_w[idx * 75 + k];
        ws[WS_SB + idx] = s;
    }
    for (int idx = t; idx < 50 * 80; idx += stride) {       // w3t[k][c]
        int k = idx / 80, c = idx % 80;
        ws[WS_W3T + idx] = (c < 75) ? conv3_w[c * 50 + k] : 0.f;
    }
    for (int idx = t; idx < 150 * 128; idx += stride) {     // w4t[k][o]
        int k = idx / 128, o = idx % 128;
        ws[WS_W4T + idx] = (o < 125) ? conv4_w[o * 150 + k] : 0.f;
    }
    for (int idx = t; idx < 75 * 128; idx += stride) {      // wbt[k][o]
        int k = idx / 128, o = idx % 128;
        ws[WS_WBT + idx] = (o < 125) ? convb_w[o * 75 + k] : 0.f;
    }
}

// ---------------- main fused kernel ----------------
// Block = 2 batch elements, 256 threads (4 waves).
__global__ __launch_bounds__(256) void net_kernel(
    const float* __restrict__ X,
    const float* __restrict__ w1,        // conv1_w [5][3]
    const float* __restrict__ l1w,       // [18][27]
    const float* __restrict__ w2,        // conv2_w [25][5][3]
    const float* __restrict__ cvaw,      // conva_w [25]
    const float* __restrict__ conv3_b,   // [75]
    const float* __restrict__ l2w,       // [9][18]
    const float* __restrict__ l2b,       // [9]
    const float* __restrict__ conv4_b,   // [125]
    const float* __restrict__ rbw,       // [9][18]
    const float* __restrict__ rbb,       // [9]
    const float* __restrict__ convb_b,   // [125]
    const float* __restrict__ ws,
    float* __restrict__ OUT)
{
    __shared__ float s_l1[486], s_Q[486], s_P[324], s_w1[15], s_bz1[90];
    __shared__ float s_w2[375], s_cvaw[25], s_bx1[450], s_sp[18], s_l2b[9], s_rbb[9];
    __shared__ float s_x[2][135];
    __shared__ float s_xl[2][90], s_xr[2][90];
    __shared__ float s_v[2][450];        // v[c][h][j] (transformed pre-conv2)
    __shared__ float s_x1[2][2250];      // x1t[c][h][j18]
    __shared__ float s_z3[2][2700];      // u (first 450) then z3r[c75][h4][j9]

    const int t = threadIdx.x;
    const long b0 = (long)blockIdx.x * 2;

    // ---- S0: stage weights + inputs ----
    for (int i = t; i < 486; i += 256) s_l1[i] = l1w[i];
    for (int i = t; i < 486; i += 256) s_Q[i] = ws[WS_Q + i];
    for (int i = t; i < 324; i += 256) s_P[i] = (i < 162) ? l2w[i] : rbw[i - 162];
    if (t < 15) s_w1[t] = w1[t];
    for (int i = t; i < 90; i += 256) s_bz1[i] = ws[WS_BZ1 + i];
    for (int i = t; i < 375; i += 256) s_w2[i] = w2[i];
    if (t < 25) s_cvaw[t] = cvaw[t];
    for (int i = t; i < 450; i += 256) s_bx1[i] = ws[WS_BX1 + i];
    if (t < 18) s_sp[t] = ws[WS_SP + t];
    if (t < 9)  s_l2b[t] = l2b[t];
    if (t < 9)  s_rbb[t] = rbb[t];
    for (int i = t; i < 270; i += 256) {
        int el = i / 135, k = i % 135;
        s_x[el][k] = X[(b0 + el) * 135 + k];
    }
    __syncthreads();

    // ---- S1: xl = x@l1^T, xr = x@Q^T  (360 tasks, 27 MACs each) ----
    for (int i = t; i < 360; i += 256) {
        int which = i / 180, r = i % 180;
        int el = r / 90, rr = r % 90, h = rr / 18, o = rr % 18;
        const float* W = which ? s_Q : s_l1;
        float s = 0.f;
        #pragma unroll
        for (int w = 0; w < 27; w++) s = fmaf(s_x[el][h * 27 + w], W[o * 27 + w], s);
        if (which) s_xr[el][h * 18 + o] = s; else s_xl[el][h * 18 + o] = s;
    }
    __syncthreads();

    // ---- S2: u = relu(conv1_H(xl) + bias_z1)  -> s_z3[el][0:450] ----
    for (int i = t; i < 900; i += 256) {
        int el = i / 450, r = i % 450;
        int c = r / 90, rr = r % 90, h = rr / 18, o = rr % 18;
        float s = s_bz1[c * 18 + o];
        #pragma unroll
        for (int dh = 0; dh < 3; dh++) {
            int hh = h + dh - 1;
            if (hh >= 0 && hh < 5) s = fmaf(s_xl[el][hh * 18 + o], s_w1[c * 3 + dh], s);
        }
        s_z3[el][r] = fmaxf(s, 0.f);   // index (c*5+h)*18+o == r
    }
    __syncthreads();

    // ---- S3: v = u @ P^T  (900 tasks, 18 MACs) ----
    for (int i = t; i < 900; i += 256) {
        int el = i / 450, r = i % 450;
        int ch = r / 18, j = r % 18;
        float s = 0.f;
        #pragma unroll
        for (int w = 0; w < 18; w++) s = fmaf(s_z3[el][ch * 18 + w], s_P[j * 18 + w], s);
        s_v[el][r] = s;
    }
    __syncthreads();

    // ---- S4: x1t = conv2_H(v) + cvaw[o]*xr + biasX1  (4500 tasks, 15 MACs) ----
    for (int i = t; i < 4500; i += 256) {
        int el = i / 2250, r = i % 2250;
        int o = r / 90, rr = r % 90, h = rr / 18, j = rr % 18;
        float s = fmaf(s_cvaw[o], s_xr[el][h * 18 + j], s_bx1[o * 18 + j]);
        #pragma unroll
        for (int c = 0; c < 5; c++) {
            #pragma unroll
            for (int dh = 0; dh < 3; dh++) {
                int hh = h + dh - 1;
                if (hh >= 0 && hh < 5)
                    s = fmaf(s_v[el][(c * 5 + hh) * 18 + j], s_w2[(o * 5 + c) * 3 + dh], s);
            }
        }
        s_x1[el][r] = s;
    }
    __syncthreads();

    const int wid = __builtin_amdgcn_readfirstlane(t >> 6);
    const int lane = t & 63;

    // ---- S5: z3r = relu(conv3(x1A) + b3*S_P + l2_b)  (wave: el, c-half) ----
    {
        int el = wid & 1, ch = wid >> 1;
        int c0 = ch * 40;
        int cnt = ch ? 35 : 40;
        int q = (lane < 36) ? lane : 0;       // q = h'*9 + j
        int hp = q / 9, j = q % 9;
        float acc[40];
        #pragma unroll
        for (int i = 0; i < 40; i++) acc[i] = 0.f;
        const float* w3t = ws + WS_W3T + c0;
        const float* lx = &s_x1[el][(hp) * 18 + j];
        #pragma unroll 2
        for (int k = 0; k < 50; k++) {
            int cin = k >> 1, dh = k & 1;
            float in = lx[(cin * 5 + dh) * 18];
            const float* wrow = w3t + k * 80;
            #pragma unroll
            for (int i = 0; i < 40; i++) acc[i] = fmaf(in, wrow[i], acc[i]);
        }
        if (lane < 36) {
            float spj = s_sp[j], l2bj = s_l2b[j];
            #pragma unroll
            for (int i = 0; i < 40; i++) {
                if (i < cnt) {
                    int c = c0 + i;
                    float v = acc[i] + conv3_b[c] * spj + l2bj;
                    s_z3[el][c * 36 + q] = fmaxf(v, 0.f);
                }
            }
        }
    }
    __syncthreads();

    // ---- S6+S7: out = conv4(z3r) + convb(x1B) + biases  (wave: o-range) ----
    {
        int o0 = wid * 32;
        int el = lane >> 5, p = lane & 31;
        int pp = (p < 27) ? p : 0;            // p = h''*9 + w
        int h = pp / 9, w = pp % 9;
        float rbbw = s_rbb[w];
        float acc[32];
        #pragma unroll
        for (int i = 0; i < 32; i++) {
            int o = o0 + i;
            acc[i] = (o < 125) ? (conv4_b[o] + convb_b[o] + ws[WS_SB + o] * rbbw) : 0.f;
        }
        // conv4: K = 150 over (cin<75, dh<2), input z3r
        {
            const float* w4t = ws + WS_W4T + o0;
            const float* lz = &s_z3[el][h * 9 + w];
            #pragma unroll 2
            for (int cin = 0; cin < 75; cin++) {
                #pragma unroll
                for (int dh = 0; dh < 2; dh++) {
                    float in = lz[cin * 36 + dh * 9];
                    const float* wrow = w4t + (cin * 2 + dh) * 128;
                    #pragma unroll
                    for (int i = 0; i < 32; i++) acc[i] = fmaf(in, wrow[i], acc[i]);
                }
            }
        }
        // convb: K = 75 over (cin<25, dh<3), input x1B = x1t[:, :, 9+w]
        {
            const float* wbt = ws + WS_WBT + o0;
            const float* lx = &s_x1[el][9 + h * 18 + w];
            #pragma unroll 2
            for (int cin = 0; cin < 25; cin++) {
                #pragma unroll
                for (int dh = 0; dh < 3; dh++) {
                    float in = lx[(cin * 5 + dh) * 18];
                    const float* wrow = wbt + (cin * 3 + dh) * 128;
                    #pragma unroll
                    for (int i = 0; i < 32; i++) acc[i] = fmaf(in, wrow[i], acc[i]);
                }
            }
        }
        if (p < 27) {
            float* outp = OUT + (b0 + el) * 3375 + p;
            #pragma unroll
            for (int i = 0; i < 32; i++) {
                int o = o0 + i;
                if (o < 125) outp[o * 27] = acc[i];
            }
        }
    }
}

extern "C" void kernel_launch(void* const* d_in, const int* in_sizes, int n_in,
                              void* d_out, int out_size, void* d_ws, size_t ws_size,
                              hipStream_t stream) {
    const float* x       = (const float*)d_in[0];
    const float* conv1_w = (const float*)d_in[1];
    const float* conv1_b = (const float*)d_in[2];
    const float* l1_w    = (const float*)d_in[3];
    const float* l1_b    = (const float*)d_in[4];
    const float* conv2_w = (const float*)d_in[5];
    const float* conv2_b = (const float*)d_in[6];
    const float* ra_w    = (const float*)d_in[7];
    const float* ra_b    = (const float*)d_in[8];
    const float* conva_w = (const float*)d_in[9];
    const float* conva_b = (const float*)d_in[10];
    const float* conv3_w = (const float*)d_in[11];
    const float* conv3_b = (const float*)d_in[12];
    const float* l2_w    = (const float*)d_in[13];
    const float* l2_b    = (const float*)d_in[14];
    const float* conv4_w = (const float*)d_in[15];
    const float* conv4_b = (const float*)d_in[16];
    const float* rb_w    = (const float*)d_in[17];
    const float* rb_b    = (const float*)d_in[18];
    const float* convb_w = (const float*)d_in[19];
    const float* convb_b = (const float*)d_in[20];
    float* ws = (float*)d_ws;
    float* out = (float*)d_out;

    const int B = in_sizes[0] / 135;

    hipLaunchKernelGGL(precompute_kernel, dim3(64), dim3(256), 0, stream,
                       conv1_b, l1_w, l1_b, conv2_b, ra_w, ra_b, conva_w, conva_b,
                       conv3_w, l2_w, conv4_w, rb_w, convb_w, ws);

    hipLaunchKernelGGL(net_kernel, dim3(B / 2), dim3(256), 0, stream,
                       x, conv1_w, l1_w, conv2_w, conva_w, conv3_b, l2_w, l2_b,
                       conv4_b, rb_w, rb_b, convb_b, ws, out);
}

// Round 3
// 1321.759 us; speedup vs baseline: 1.5181x; 1.5181x over previous
//
#include <hip/hip_runtime.h>

// ---------------- workspace layout (floats) ----------------
#define WS_Q    0        // Q[18][27] = P @ ra_w
#define WS_BZ1  486      // bias_z1[5][18]
#define WS_BX1  576      // biasX1[25][18]
#define WS_SP   1026     // S_P[18]
#define WS_SB   1044     // Sb[125] = row sums of convb_w
#define WS_W3T  1172     // w3t[50][80]   (k=cin*2+dh, padded to 80)
#define WS_W4T  5172     // w4t[150][128] (k=cin*2+dh, padded to 128)
#define WS_WBT  24372    // wbt[75][128]  (k=cin*3+dh, padded to 128)
#define WS_TOTAL 33972

// ---------------- shared memory layout (floats) ----------------
// Peak-live analysis: x1 (4500) + z3 (5400) + small (36) = 9936 floats = 39744 B
// -> 4 blocks/CU (was 55296 B -> 2 blocks/CU). Everything early-stage lives in
// the z3 region (dead before S5 writes z3).
#define SM_X1   0        // x1t[el][2250]                 live S4..S6
#define SM_Z3   4500     // z3r[el][2700]                 live S5..S6
#define SM_U    4500     // u[el][450]                    live S2..S3
#define SM_L1   5400     // l1w [486]                     live S1
#define SM_Q    5886     // Q   [486]                     live S1
#define SM_P    6372     // P   [324]                     live S3
#define SM_W1   6696     // conv1_w [15]                  live S2
#define SM_BZ1  6711     // bias_z1 [90]                  live S2
#define SM_W2   6801     // conv2_w [375]                 live S4
#define SM_CVA  7176     // conva_w [25]                  live S4
#define SM_BX1  7201     // biasX1 [450]                  live S4
#define SM_XIN  7651     // x[el][135]                    live S1
#define SM_XLP  7921     // xl padded [el][7][18]         live S1..S2
#define SM_XR   8173     // xr[el][90]                    live S1..S4
#define SM_VP   8353     // v padded [el][5][7][18]       live S3..S4
#define SM_SP   9900     // S_P [18]                      live S5
#define SM_L2B  9918     // l2_b [9]                      live S5
#define SM_RBB  9927     // rb_b [9]                      live S6
#define SM_TOT  9936

// ---------------- precompute kernel ----------------
__global__ void precompute_kernel(
    const float* __restrict__ conv1_b, const float* __restrict__ l1_w, const float* __restrict__ l1_b,
    const float* __restrict__ conv2_b, const float* __restrict__ ra_w, const float* __restrict__ ra_b,
    const float* __restrict__ conva_w, const float* __restrict__ conva_b,
    const float* __restrict__ conv3_w, const float* __restrict__ l2_w,
    const float* __restrict__ conv4_w, const float* __restrict__ rb_w,
    const float* __restrict__ convb_w, float* __restrict__ ws)
{
    int t = blockIdx.x * blockDim.x + threadIdx.x;
    int stride = gridDim.x * blockDim.x;
    auto P = [&](int j, int o) -> float {
        return (j < 9) ? l2_w[j * 18 + o] : rb_w[(j - 9) * 18 + o];
    };
    for (int idx = t; idx < 486; idx += stride) {           // Q = P @ ra_w  [18][27]
        int j = idx / 27, w = idx % 27;
        float s = 0.f;
        for (int o = 0; o < 18; o++) s += P(j, o) * ra_w[o * 27 + w];
        ws[WS_Q + idx] = s;
    }
    for (int idx = t; idx < 90; idx += stride) {            // bias_z1[c][o]
        int c = idx / 18, o = idx % 18;
        float sl = 0.f;
        for (int w = 0; w < 27; w++) sl += l1_w[o * 27 + w];
        ws[WS_BZ1 + idx] = conv1_b[c] * sl + l1_b[o];
    }
    for (int idx = t; idx < 450; idx += stride) {           // biasX1[o][j]
        int o = idx / 18, j = idx % 18;
        float sp = 0.f, rab = 0.f;
        for (int w = 0; w < 18; w++) { float p = P(j, w); sp += p; rab += ra_b[w] * p; }
        ws[WS_BX1 + idx] = conv2_b[o] * sp + conva_w[o] * rab + conva_b[o] * sp;
    }
    for (int idx = t; idx < 18; idx += stride) {            // S_P[j]
        float sp = 0.f;
        for (int w = 0; w < 18; w++) sp += P(idx, w);
        ws[WS_SP + idx] = sp;
    }
    for (int idx = t; idx < 125; idx += stride) {           // Sb[o]
        float s = 0.f;
        for (int k = 0; k < 75; k++) s += convb_w[idx * 75 + k];
        ws[WS_SB + idx] = s;
    }
    for (int idx = t; idx < 50 * 80; idx += stride) {       // w3t[k][c]
        int k = idx / 80, c = idx % 80;
        ws[WS_W3T + idx] = (c < 75) ? conv3_w[c * 50 + k] : 0.f;
    }
    for (int idx = t; idx < 150 * 128; idx += stride) {     // w4t[k][o]
        int k = idx / 128, o = idx % 128;
        ws[WS_W4T + idx] = (o < 125) ? conv4_w[o * 150 + k] : 0.f;
    }
    for (int idx = t; idx < 75 * 128; idx += stride) {      // wbt[k][o]
        int k = idx / 128, o = idx % 128;
        ws[WS_WBT + idx] = (o < 125) ? convb_w[o * 75 + k] : 0.f;
    }
}

// ---------------- main fused kernel ----------------
// Block = 2 batch elements, 256 threads (4 waves), 39744 B LDS -> 4 blocks/CU.
__global__ __launch_bounds__(256) void net_kernel(
    const float* __restrict__ X,
    const float* __restrict__ w1,        // conv1_w [5][3]
    const float* __restrict__ l1w,       // [18][27]
    const float* __restrict__ w2,        // conv2_w [25][5][3]
    const float* __restrict__ cvaw,      // conva_w [25]
    const float* __restrict__ conv3_b,   // [75]
    const float* __restrict__ l2w,       // [9][18]
    const float* __restrict__ l2b,       // [9]
    const float* __restrict__ conv4_b,   // [125]
    const float* __restrict__ rbw,       // [9][18]
    const float* __restrict__ rbb,       // [9]
    const float* __restrict__ convb_b,   // [125]
    const float* __restrict__ ws,
    float* __restrict__ OUT)
{
    __shared__ float smem[SM_TOT];

    const int t = threadIdx.x;
    const long b0 = (long)blockIdx.x * 2;

    // ---- S0: stage weights + inputs + zero pads ----
    for (int i = t; i < 486; i += 256) smem[SM_L1 + i] = l1w[i];
    for (int i = t; i < 486; i += 256) smem[SM_Q + i] = ws[WS_Q + i];
    for (int i = t; i < 324; i += 256) smem[SM_P + i] = (i < 162) ? l2w[i] : rbw[i - 162];
    if (t < 15) smem[SM_W1 + t] = w1[t];
    for (int i = t; i < 90; i += 256) smem[SM_BZ1 + i] = ws[WS_BZ1 + i];
    for (int i = t; i < 375; i += 256) smem[SM_W2 + i] = w2[i];
    if (t < 25) smem[SM_CVA + t] = cvaw[t];
    for (int i = t; i < 450; i += 256) smem[SM_BX1 + i] = ws[WS_BX1 + i];
    if (t < 18) smem[SM_SP + t] = ws[WS_SP + t];
    if (t < 9)  smem[SM_L2B + t] = l2b[t];
    if (t < 9)  smem[SM_RBB + t] = rbb[t];
    for (int i = t; i < 270; i += 256) {
        int el = i / 135, k = i % 135;
        smem[SM_XIN + el * 135 + k] = X[(b0 + el) * 135 + k];
    }
    for (int i = t; i < 72; i += 256) {        // xl pad rows (hh=0,6)
        int el = i / 36, rr = i % 36;
        smem[SM_XLP + el * 126 + (rr / 18) * 6 * 18 + (rr % 18)] = 0.f;
    }
    for (int i = t; i < 360; i += 256) {       // v pad rows (hh=0,6 per channel)
        int el = i / 180, rr = i % 180;
        int c = rr / 36, r2 = rr % 36;
        smem[SM_VP + el * 630 + (c * 7 + (r2 / 18) * 6) * 18 + (r2 % 18)] = 0.f;
    }
    __syncthreads();

    // ---- S1: xl = x@l1^T (into padded rows 1..5), xr = x@Q^T ----
    for (int i = t; i < 360; i += 256) {
        int which = i / 180, r = i % 180;
        int el = r / 90, rr = r % 90, h = rr / 18, o = rr % 18;
        const float* W = smem + (which ? SM_Q : SM_L1) + o * 27;
        const float* xx = smem + SM_XIN + el * 135 + h * 27;
        float s = 0.f;
        #pragma unroll
        for (int w = 0; w < 27; w++) s = fmaf(xx[w], W[w], s);
        if (which) smem[SM_XR + el * 90 + h * 18 + o] = s;
        else       smem[SM_XLP + el * 126 + (h + 1) * 18 + o] = s;
    }
    __syncthreads();

    // ---- S2: u = relu(conv1_H(xl) + bias_z1) -- branch-free via pad ----
    for (int i = t; i < 900; i += 256) {
        int el = i / 450, r = i % 450;
        int c = r / 90, rr = r % 90, h = rr / 18, o = rr % 18;
        const float* xl = smem + SM_XLP + el * 126 + h * 18 + o;
        float s = smem[SM_BZ1 + c * 18 + o];
        #pragma unroll
        for (int dh = 0; dh < 3; dh++)
            s = fmaf(xl[dh * 18], smem[SM_W1 + c * 3 + dh], s);
        smem[SM_U + el * 450 + r] = fmaxf(s, 0.f);   // layout (c*5+h)*18+o
    }
    __syncthreads();

    // ---- S3: v = u @ P^T  (into padded rows) ----
    for (int i = t; i < 900; i += 256) {
        int el = i / 450, r = i % 450;
        int ch = r / 18, j = r % 18;
        int c = ch / 5, h = ch % 5;
        const float* uu = smem + SM_U + el * 450 + ch * 18;
        const float* Pr = smem + SM_P + j * 18;
        float s = 0.f;
        #pragma unroll
        for (int w = 0; w < 18; w++) s = fmaf(uu[w], Pr[w], s);
        smem[SM_VP + el * 630 + (c * 7 + h + 1) * 18 + j] = s;
    }
    __syncthreads();

    // ---- S4: x1t = conv2_H(v) + cvaw[o]*xr + biasX1 -- branch-free ----
    for (int i = t; i < 4500; i += 256) {
        int el = i / 2250, r = i % 2250;
        int o = r / 90, rr = r % 90, h = rr / 18, j = rr % 18;
        float s = fmaf(smem[SM_CVA + o], smem[SM_XR + el * 90 + h * 18 + j],
                       smem[SM_BX1 + o * 18 + j]);
        const float* vb = smem + SM_VP + el * 630 + h * 18 + j;
        const float* wb = smem + SM_W2 + o * 15;
        #pragma unroll
        for (int c = 0; c < 5; c++) {
            #pragma unroll
            for (int dh = 0; dh < 3; dh++)
                s = fmaf(vb[(c * 7 + dh) * 18], wb[c * 3 + dh], s);
        }
        smem[SM_X1 + el * 2250 + r] = s;
    }
    __syncthreads();

    const int wid = __builtin_amdgcn_readfirstlane(t >> 6);
    const int lane = t & 63;

    // ---- S5: z3r = relu(conv3(x1A) + b3*S_P + l2_b)  (wave: el, c-half) ----
    {
        int el = wid & 1, ch = wid >> 1;
        int c0 = ch * 40;
        int cnt = ch ? 35 : 40;
        int q = (lane < 36) ? lane : 0;       // q = h'*9 + j
        int hp = q / 9, j = q % 9;
        float acc[40];
        #pragma unroll
        for (int i = 0; i < 40; i++) acc[i] = 0.f;
        const float* w3t = ws + WS_W3T + c0;
        const float* lx = smem + SM_X1 + el * 2250 + hp * 18 + j;
        #pragma unroll 2
        for (int k = 0; k < 50; k++) {
            int cin = k >> 1, dh = k & 1;
            float in = lx[(cin * 5 + dh) * 18];
            const float* wrow = w3t + k * 80;
            #pragma unroll
            for (int i = 0; i < 40; i++) acc[i] = fmaf(in, wrow[i], acc[i]);
        }
        if (lane < 36) {
            float spj = smem[SM_SP + j], l2bj = smem[SM_L2B + j];
            #pragma unroll
            for (int i = 0; i < 40; i++) {
                if (i < cnt) {
                    int c = c0 + i;
                    float v = acc[i] + conv3_b[c] * spj + l2bj;
                    smem[SM_Z3 + el * 2700 + c * 36 + q] = fmaxf(v, 0.f);
                }
            }
        }
    }
    __syncthreads();

    // ---- S6+S7: out = conv4(z3r) + convb(x1B) + biases  (wave: o-range) ----
    {
        int o0 = wid * 32;
        int el = lane >> 5, p = lane & 31;
        int pp = (p < 27) ? p : 0;            // p = h''*9 + w
        int h = pp / 9, w = pp % 9;
        float rbbw = smem[SM_RBB + w];
        float acc[32];
        #pragma unroll
        for (int i = 0; i < 32; i++) {
            int o = o0 + i;
            acc[i] = (o < 125) ? (conv4_b[o] + convb_b[o] + ws[WS_SB + o] * rbbw) : 0.f;
        }
        // conv4: K = 150 over (cin<75, dh<2), input z3r
        {
            const float* w4t = ws + WS_W4T + o0;
            const float* lz = smem + SM_Z3 + el * 2700 + h * 9 + w;
            #pragma unroll 2
            for (int cin = 0; cin < 75; cin++) {
                #pragma unroll
                for (int dh = 0; dh < 2; dh++) {
                    float in = lz[cin * 36 + dh * 9];
                    const float* wrow = w4t + (cin * 2 + dh) * 128;
                    #pragma unroll
                    for (int i = 0; i < 32; i++) acc[i] = fmaf(in, wrow[i], acc[i]);
                }
            }
        }
        // convb: K = 75 over (cin<25, dh<3), input x1B = x1t[:, :, 9+w]
        {
            const float* wbt = ws + WS_WBT + o0;
            const float* lx = smem + SM_X1 + el * 2250 + 9 + h * 18 + w;
            #pragma unroll 2
            for (int cin = 0; cin < 25; cin++) {
                #pragma unroll
                for (int dh = 0; dh < 3; dh++) {
                    float in = lx[(cin * 5 + dh) * 18];
                    const float* wrow = wbt + (cin * 3 + dh) * 128;
                    #pragma unroll
                    for (int i = 0; i < 32; i++) acc[i] = fmaf(in, wrow[i], acc[i]);
                }
            }
        }
        if (p < 27) {
            float* outp = OUT + (b0 + el) * 3375 + p;
            #pragma unroll
            for (int i = 0; i < 32; i++) {
                int o = o0 + i;
                if (o < 125) outp[o * 27] = acc[i];
            }
        }
    }
}

extern "C" void kernel_launch(void* const* d_in, const int* in_sizes, int n_in,
                              void* d_out, int out_size, void* d_ws, size_t ws_size,
                              hipStream_t stream) {
    const float* x       = (const float*)d_in[0];
    const float* conv1_w = (const float*)d_in[1];
    const float* conv1_b = (const float*)d_in[2];
    const float* l1_w    = (const float*)d_in[3];
    const float* l1_b    = (const float*)d_in[4];
    const float* conv2_w = (const float*)d_in[5];
    const float* conv2_b = (const float*)d_in[6];
    const float* ra_w    = (const float*)d_in[7];
    const float* ra_b    = (const float*)d_in[8];
    const float* conva_w = (const float*)d_in[9];
    const float* conva_b = (const float*)d_in[10];
    const float* conv3_w = (const float*)d_in[11];
    const float* conv3_b = (const float*)d_in[12];
    const float* l2_w    = (const float*)d_in[13];
    const float* l2_b    = (const float*)d_in[14];
    const float* conv4_w = (const float*)d_in[15];
    const float* conv4_b = (const float*)d_in[16];
    const float* rb_w    = (const float*)d_in[17];
    const float* rb_b    = (const float*)d_in[18];
    const float* convb_w = (const float*)d_in[19];
    const float* convb_b = (const float*)d_in[20];
    float* ws = (float*)d_ws;
    float* out = (float*)d_out;

    const int B = in_sizes[0] / 135;

    hipLaunchKernelGGL(precompute_kernel, dim3(64), dim3(256), 0, stream,
                       conv1_b, l1_w, l1_b, conv2_b, ra_w, ra_b, conva_w, conva_b,
                       conv3_w, l2_w, conv4_w, rb_w, convb_w, ws);

    hipLaunchKernelGGL(net_kernel, dim3(B / 2), dim3(256), 0, stream,
                       x, conv1_w, l1_w, conv2_w, conva_w, conv3_b, l2_w, l2_b,
                       conv4_b, rb_w, rb_b, convb_b, ws, out);
}

// Round 4
// 1133.683 us; speedup vs baseline: 1.7700x; 1.1659x over previous
//
#include <hip/hip_runtime.h>

typedef unsigned short u16;
typedef __attribute__((ext_vector_type(8))) short bf16x8;
typedef __attribute__((ext_vector_type(4))) float f32x4;

// ---------------- workspace layout ----------------
// float region (float indices)
#define F_BZ1 0       // [90]   bias for u: [c][o]
#define F_BX1 90      // [450]  bias for x1: [o][j]
#define F_B3  540     // [80*9] bias for z3: [c][j]
#define F_BO  1260    // [128*9] bias for out: [o][w]
// ushort (bf16) region starts at byte 9664 (16B aligned)
#define WS_US_BYTE 9664
#define T_G1 0        // [112][96]  n=(c*18+o | 90+j) , k=dh*32+w
#define T_P  10752    // [32][32]   [j][o]
#define T_W2 11776    // [32][32]   [o][k=c*3+dh]
#define T_W3 12800    // [2][80][32]  [dh][c][cin]
#define T_W4 17920    // [128][192]   [o][dh*96+c]
#define T_WB 42496    // [128][96]    [o][dh*32+cin]

__device__ __host__ inline u16 f2b_(float f) {
    union { float f; unsigned u; } v; v.f = f;
    unsigned r = v.u + 0x7FFFu + ((v.u >> 16) & 1u);
    return (u16)(r >> 16);
}
__device__ inline float b2f_(u16 u) {
    union { unsigned u; float f; } v; v.u = ((unsigned)u) << 16;
    return v.f;
}

// ---------------- precompute kernel ----------------
__global__ void precompute_kernel(
    const float* __restrict__ conv1_w, const float* __restrict__ conv1_b,
    const float* __restrict__ l1_w, const float* __restrict__ l1_b,
    const float* __restrict__ conv2_w, const float* __restrict__ conv2_b,
    const float* __restrict__ ra_w, const float* __restrict__ ra_b,
    const float* __restrict__ conva_w, const float* __restrict__ conva_b,
    const float* __restrict__ conv3_w, const float* __restrict__ conv3_b,
    const float* __restrict__ l2_w, const float* __restrict__ l2_b,
    const float* __restrict__ conv4_w, const float* __restrict__ conv4_b,
    const float* __restrict__ rb_w, const float* __restrict__ rb_b,
    const float* __restrict__ convb_w, const float* __restrict__ convb_b,
    float* __restrict__ wsf, u16* __restrict__ wsu)
{
    int t0 = blockIdx.x * blockDim.x + threadIdx.x;
    int stride = gridDim.x * blockDim.x;
    auto P = [&](int j, int o) -> float {
        return (j < 9) ? l2_w[j * 18 + o] : rb_w[(j - 9) * 18 + o];
    };
    // T_G1 [112][96]: combined conv1 x l1 weights + Q (= P @ ra_w) rows
    for (int i = t0; i < 112 * 96; i += stride) {
        int n = i / 96, k = i % 96;
        int dh = k / 32, w = k % 32;
        float val = 0.f;
        if (w < 27) {
            if (n < 90) {
                int c = n / 18, o = n % 18;
                val = conv1_w[c * 3 + dh] * l1_w[o * 27 + w];
            } else if (n < 108 && dh == 1) {
                int j = n - 90; float q = 0.f;
                for (int o = 0; o < 18; o++) q += P(j, o) * ra_w[o * 27 + w];
                val = q;
            }
        }
        wsu[T_G1 + i] = f2b_(val);
    }
    // T_P [32][32]
    for (int i = t0; i < 1024; i += stride) {
        int j = i / 32, o = i % 32;
        wsu[T_P + i] = f2b_((j < 18 && o < 18) ? P(j, o) : 0.f);
    }
    // T_W2 [32][32]: [o][k=c*3+dh]
    for (int i = t0; i < 1024; i += stride) {
        int o = i / 32, k = i % 32;
        wsu[T_W2 + i] = f2b_((o < 25 && k < 15) ? conv2_w[o * 15 + k] : 0.f);
    }
    // T_W3 [2][80][32]
    for (int i = t0; i < 5120; i += stride) {
        int dh = i / 2560, r = i % 2560, c = r / 32, cin = r % 32;
        wsu[T_W3 + i] = f2b_((c < 75 && cin < 25) ? conv3_w[(c * 25 + cin) * 2 + dh] : 0.f);
    }
    // T_W4 [128][192]
    for (int i = t0; i < 128 * 192; i += stride) {
        int o = i / 192, kk = i % 192, dh = kk / 96, c = kk % 96;
        wsu[T_W4 + i] = f2b_((o < 125 && c < 75) ? conv4_w[(o * 75 + c) * 2 + dh] : 0.f);
    }
    // T_WB [128][96]
    for (int i = t0; i < 128 * 96; i += stride) {
        int o = i / 96, kk = i % 96, dh = kk / 32, cin = kk % 32;
        wsu[T_WB + i] = f2b_((o < 125 && cin < 25) ? convb_w[(o * 25 + cin) * 3 + dh] : 0.f);
    }
    // F_BZ1 [90]
    for (int i = t0; i < 90; i += stride) {
        int c = i / 18, o = i % 18;
        float s = 0.f;
        for (int w = 0; w < 27; w++) s += l1_w[o * 27 + w];
        wsf[F_BZ1 + i] = conv1_b[c] * s + l1_b[o];
    }
    // F_BX1 [450]
    for (int i = t0; i < 450; i += stride) {
        int o = i / 18, j = i % 18;
        float sp = 0.f, rab = 0.f;
        for (int w = 0; w < 18; w++) { float p = P(j, w); sp += p; rab += ra_b[w] * p; }
        wsf[F_BX1 + i] = conv2_b[o] * sp + conva_w[o] * rab + conva_b[o] * sp;
    }
    // F_B3 [720]
    for (int i = t0; i < 720; i += stride) {
        int c = i / 9, j = i % 9;
        float val = 0.f;
        if (c < 75) {
            float s = 0.f;
            for (int w = 0; w < 18; w++) s += l2_w[j * 18 + w];
            val = conv3_b[c] * s + l2_b[j];
        }
        wsf[F_B3 + i] = val;
    }
    // F_BO [1152]
    for (int i = t0; i < 1152; i += stride) {
        int o = i / 9, w = i % 9;
        float val = 0.f;
        if (o < 125) {
            float sb = 0.f;
            for (int k = 0; k < 75; k++) sb += convb_w[o * 75 + k];
            val = conv4_b[o] + convb_b[o] + sb * rb_b[w];
        }
        wsf[F_BO + i] = val;
    }
}

// ---------------- shared memory layout (ushort indices) ----------------
#define SM_X1T 0       // [8][5][18][40]  = 28800  x1t bf16, k=o(25,pad40)
#define SM_Z3T 28800   // [8][36][104]    = 29952  z3 bf16, k=c(75/96,pad104)
// overlay inside Z3T region (dead before G4 writes z3):
#define SM_U   28800   // [200][40]  u bf16, k=o(18,pad... reads k<32)
#define SM_XIM 36800   // [40][104]  x im2col bf16, k=dh*32+w (96, pad104)
#define SM_XR  40960   // [8][5][18] xr bf16
#define SM_VIM 41680   // [724][16]  conv2 im2col bf16, k=c*3+dh (15,pad16)
#define SM_TOT 58752   // ushorts = 117504 B

#define MFMA(a,b,c) __builtin_amdgcn_mfma_f32_16x16x32_bf16((a),(b),(c),0,0,0)

// ---------------- main fused kernel ----------------
// Block = 8 batch elements, 512 threads (8 waves), 117.5 KB LDS -> 1 block/CU.
__global__ __launch_bounds__(512, 1) void net_kernel(
    const float* __restrict__ X,
    const float* __restrict__ conva_w,
    const float* __restrict__ wsf,
    const u16* __restrict__ wsu,
    float* __restrict__ OUT)
{
    __shared__ u16 smem[SM_TOT];
    const int t = threadIdx.x;
    const int wid = t >> 6;
    const int lane = t & 63;
    const int l15 = lane & 15;
    const int kg = lane >> 4;
    const long b0 = (long)blockIdx.x * 8;

    // ---- S0a: zero X1T + overlay region [0, 53264) ----
    {
        float4* p = (float4*)smem;
        float4 z = make_float4(0.f, 0.f, 0.f, 0.f);
        for (int i = t; i < 6658; i += 512) p[i] = z;   // 6658*8 = 53264 ushorts
    }
    __syncthreads();
    // ---- S0b: fill x im2col ----
    for (int i = t; i < 3240; i += 512) {
        int w = i % 27, r = i / 27;          // r < 120
        int dh = r % 3, eh = r / 3;          // eh = el*5+h < 40
        int el = eh / 5, h = eh % 5;
        int hh = h + dh - 1;
        if (hh >= 0 && hh < 5)
            smem[SM_XIM + eh * 104 + dh * 32 + w] = f2b_(X[(b0 + el) * 135 + hh * 27 + w]);
    }
    __syncthreads();

    // ---- G1: [u | xr] = x_im @ T_G1^T.  M=40(3mt) N=108(7nt) K=96(3ks) ----
    for (int ti = wid; ti < 21; ti += 8) {
        int mt = ti / 7, nt = ti % 7;
        int n = nt * 16 + l15;
        int ma = mt * 16 + l15; if (ma > 39) ma = 39;
        f32x4 acc = {0.f, 0.f, 0.f, 0.f};
        #pragma unroll
        for (int ks = 0; ks < 3; ks++) {
            bf16x8 a = *(const bf16x8*)&smem[SM_XIM + ma * 104 + ks * 32 + kg * 8];
            bf16x8 b = *(const bf16x8*)&wsu[T_G1 + n * 96 + ks * 32 + kg * 8];
            acc = MFMA(a, b, acc);
        }
        float bias = (n < 90) ? wsf[F_BZ1 + n] : 0.f;
        #pragma unroll
        for (int r = 0; r < 4; r++) {
            int m = mt * 16 + kg * 4 + r;
            if (m < 40) {
                int el = m / 5, h = m % 5;
                if (n < 90) {
                    int c = n / 18, o = n % 18;
                    float v = fmaxf(acc[r] + bias, 0.f);
                    smem[SM_U + (el * 25 + c * 5 + h) * 40 + o] = f2b_(v);
                } else if (n < 108) {
                    smem[SM_XR + (el * 5 + h) * 18 + (n - 90)] = f2b_(acc[r]);
                }
            }
        }
    }
    __syncthreads();

    // ---- G2: v = u @ P^T.  M=200(13mt) N=18(2nt) K=32(1ks); scatter to v_im ----
    for (int ti = wid; ti < 26; ti += 8) {
        int mt = ti >> 1, nt = ti & 1;
        int n = nt * 16 + l15;               // j
        int ma = mt * 16 + l15; if (ma > 199) ma = 199;
        bf16x8 a = *(const bf16x8*)&smem[SM_U + ma * 40 + kg * 8];
        bf16x8 b = *(const bf16x8*)&wsu[T_P + n * 32 + kg * 8];
        f32x4 acc = {0.f, 0.f, 0.f, 0.f};
        acc = MFMA(a, b, acc);
        if (n < 18) {
            #pragma unroll
            for (int r = 0; r < 4; r++) {
                int m = mt * 16 + kg * 4 + r;
                if (m < 200) {
                    int el = m / 25, c = (m / 5) % 5, h = m % 5;
                    u16 bv = f2b_(acc[r]);
                    #pragma unroll
                    for (int dh = 0; dh < 3; dh++) {
                        int ho = h + 1 - dh;
                        if (ho >= 0 && ho < 5)
                            smem[SM_VIM + (el * 90 + ho * 18 + n) * 16 + c * 3 + dh] = bv;
                    }
                }
            }
        }
    }
    __syncthreads();

    // ---- G3: x1 = v_im @ w2^T + cva*xr + bias.  M=720(45mt) N=25(2nt) K=16(pad32) ----
    for (int ti = wid; ti < 90; ti += 8) {
        int mt = ti >> 1, nt = ti & 1;
        int n = nt * 16 + l15;               // o
        int ma = mt * 16 + l15;              // < 720 exact
        // reads k 0..31: k>=16 spills into next v_im row (finite), B is zero there
        bf16x8 a = *(const bf16x8*)&smem[SM_VIM + ma * 16 + kg * 8];
        bf16x8 b = *(const bf16x8*)&wsu[T_W2 + n * 32 + kg * 8];
        f32x4 acc = {0.f, 0.f, 0.f, 0.f};
        acc = MFMA(a, b, acc);
        if (n < 25) {
            float cva = conva_w[n];
            #pragma unroll
            for (int r = 0; r < 4; r++) {
                int m = mt * 16 + kg * 4 + r;
                int el = m / 90, rr = m % 90, h = rr / 18, j = rr % 18;
                float xr = b2f_(smem[SM_XR + (el * 5 + h) * 18 + j]);
                float v = acc[r] + cva * xr + wsf[F_BX1 + n * 18 + j];
                smem[SM_X1T + ((el * 5 + h) * 18 + j) * 40 + n] = f2b_(v);
            }
        }
    }
    __syncthreads();

    // ---- G4: z3 = relu(conv3(x1A) + b3).  M=288(18mt) N=75(5nt) K=2x32(dh) ----
    // zero z3T pad cols 75..95 (overlay region is dead now)
    for (int i = t; i < 6048; i += 512) {
        int c = 75 + i % 21, rq = i / 21;    // rq < 288
        smem[SM_Z3T + rq * 104 + c] = 0;
    }
    for (int mt = wid; mt < 18; mt += 8) {
        int ma = mt * 16 + l15;              // < 288 exact
        int el = ma / 36, q = ma % 36, hp = q / 9, jj = q % 9;
        f32x4 acc[5];
        #pragma unroll
        for (int i = 0; i < 5; i++) acc[i] = (f32x4){0.f, 0.f, 0.f, 0.f};
        #pragma unroll
        for (int dh = 0; dh < 2; dh++) {
            bf16x8 a = *(const bf16x8*)&smem[SM_X1T + ((el * 5 + hp + dh) * 18 + jj) * 40 + kg * 8];
            #pragma unroll
            for (int nt = 0; nt < 5; nt++) {
                bf16x8 b = *(const bf16x8*)&wsu[T_W3 + (dh * 80 + nt * 16 + l15) * 32 + kg * 8];
                acc[nt] = MFMA(a, b, acc[nt]);
            }
        }
        #pragma unroll
        for (int nt = 0; nt < 5; nt++) {
            int c = nt * 16 + l15;
            if (c < 75) {
                #pragma unroll
                for (int r = 0; r < 4; r++) {
                    int m = mt * 16 + kg * 4 + r;
                    int eld = m / 36, qd = m % 36, jd = qd % 9;
                    float v = fmaxf(acc[nt][r] + wsf[F_B3 + c * 9 + jd], 0.f);
                    smem[SM_Z3T + (eld * 36 + qd) * 104 + c] = f2b_(v);
                }
            }
        }
    }
    __syncthreads();

    // ---- G5+G6: out = conv4(z3) + convb(x1B) + bias.  M=216(14mt) N=125(8nt) ----
    {
        int g = wid >> 1, nh = wid & 1, o0 = nh * 64;
        bf16x8 B5[24];
        #pragma unroll
        for (int dh = 0; dh < 2; dh++)
            #pragma unroll
            for (int ks = 0; ks < 3; ks++)
                #pragma unroll
                for (int nt = 0; nt < 4; nt++)
                    B5[(dh * 3 + ks) * 4 + nt] =
                        *(const bf16x8*)&wsu[T_W4 + (o0 + nt * 16 + l15) * 192 + dh * 96 + ks * 32 + kg * 8];
        bf16x8 B6[12];
        #pragma unroll
        for (int dh = 0; dh < 3; dh++)
            #pragma unroll
            for (int nt = 0; nt < 4; nt++)
                B6[dh * 4 + nt] =
                    *(const bf16x8*)&wsu[T_WB + (o0 + nt * 16 + l15) * 96 + dh * 32 + kg * 8];

        for (int mi = 0; mi < 4; mi++) {
            int mt = g + mi * 4;
            if (mt >= 14) break;
            int ma = mt * 16 + l15; if (ma > 215) ma = 215;
            int el = ma / 27, p = ma % 27, hpp = p / 9, w = p % 9;
            f32x4 acc[4];
            #pragma unroll
            for (int i = 0; i < 4; i++) acc[i] = (f32x4){0.f, 0.f, 0.f, 0.f};
            // conv4 over z3T
            #pragma unroll
            for (int dh = 0; dh < 2; dh++) {
                int rowb = SM_Z3T + (el * 36 + (hpp + dh) * 9 + w) * 104;
                #pragma unroll
                for (int ks = 0; ks < 3; ks++) {
                    bf16x8 a = *(const bf16x8*)&smem[rowb + ks * 32 + kg * 8];
                    #pragma unroll
                    for (int nt = 0; nt < 4; nt++)
                        acc[nt] = MFMA(a, B5[(dh * 3 + ks) * 4 + nt], acc[nt]);
                }
            }
            // convb over x1B (j = 9+w)
            #pragma unroll
            for (int dh = 0; dh < 3; dh++) {
                bf16x8 a = *(const bf16x8*)&smem[SM_X1T + ((el * 5 + hpp + dh) * 18 + 9 + w) * 40 + kg * 8];
                #pragma unroll
                for (int nt = 0; nt < 4; nt++)
                    acc[nt] = MFMA(a, B6[dh * 4 + nt], acc[nt]);
            }
            // epilogue + store
            #pragma unroll
            for (int nt = 0; nt < 4; nt++) {
                int o = o0 + nt * 16 + l15;
                if (o < 125) {
                    #pragma unroll
                    for (int r = 0; r < 4; r++) {
                        int m = mt * 16 + kg * 4 + r;
                        if (m < 216) {
                            int eld = m / 27, pd = m % 27;
                            float v = acc[nt][r] + wsf[F_BO + o * 9 + pd % 9];
                            OUT[(b0 + eld) * 3375 + o * 27 + pd] = v;
                        }
                    }
                }
            }
        }
    }
}

extern "C" void kernel_launch(void* const* d_in, const int* in_sizes, int n_in,
                              void* d_out, int out_size, void* d_ws, size_t ws_size,
                              hipStream_t stream) {
    const float* x       = (const float*)d_in[0];
    const float* conv1_w = (const float*)d_in[1];
    const float* conv1_b = (const float*)d_in[2];
    const float* l1_w    = (const float*)d_in[3];
    const float* l1_b    = (const float*)d_in[4];
    const float* conv2_w = (const float*)d_in[5];
    const float* conv2_b = (const float*)d_in[6];
    const float* ra_w    = (const float*)d_in[7];
    const float* ra_b    = (const float*)d_in[8];
    const float* conva_w = (const float*)d_in[9];
    const float* conva_b = (const float*)d_in[10];
    const float* conv3_w = (const float*)d_in[11];
    const float* conv3_b = (const float*)d_in[12];
    const float* l2_w    = (const float*)d_in[13];
    const float* l2_b    = (const float*)d_in[14];
    const float* conv4_w = (const float*)d_in[15];
    const float* conv4_b = (const float*)d_in[16];
    const float* rb_w    = (const float*)d_in[17];
    const float* rb_b    = (const float*)d_in[18];
    const float* convb_w = (const float*)d_in[19];
    const float* convb_b = (const float*)d_in[20];

    float* wsf = (float*)d_ws;
    u16*   wsu = (u16*)((char*)d_ws + WS_US_BYTE);
    float* out = (float*)d_out;

    const int B = in_sizes[0] / 135;

    hipLaunchKernelGGL(precompute_kernel, dim3(64), dim3(256), 0, stream,
                       conv1_w, conv1_b, l1_w, l1_b, conv2_w, conv2_b,
                       ra_w, ra_b, conva_w, conva_b, conv3_w, conv3_b,
                       l2_w, l2_b, conv4_w, conv4_b, rb_w, rb_b,
                       convb_w, convb_b, wsf, wsu);

    hipLaunchKernelGGL(net_kernel, dim3(B / 8), dim3(512), 0, stream,
                       x, conva_w, wsf, wsu, out);
}